// Round 3
// baseline (125.204 us; speedup 1.0000x reference)
//
#include <hip/hip_runtime.h>

// ClusteringAffinity: out[n,c] = exp(-min_j (f[n]-W[c,j])^2 / 10) for c<100,
// out[n,100] = rw (pairwise-variance regularizer over the 500 centers).
//
// R3: single streaming kernel. Thread -> (8-row group G, column-quad q).
// q<25: compute 4 distance cols for 8 rows, store 8 float4s directly.
// q==25: store rw (col 100) for 8 rows. No LDS tile, no compute/store
// barrier phases, every thread productive. rw fused: wave 0 per block
// computes power sums (double) + butterfly reduce, broadcast via LDS.
//
// rw via power sums over the 500 scalar centers:
//   S1 = sum_{i<j}(wi-wj)^2 = mc*p2 - p1^2
//   Sq = sum_{i<j}(wi-wj)^4 = mc*p4 - 4*p3*p1 + 3*p2^2
//   mu = S1/P, rw = Sq/P - mu^2, P = (mc^2-mc)/2

static constexpr int N_   = 262144;
static constexpr int C_   = 100;
static constexpr int COLS = C_ + 1;   // 101
static constexpr int MC_  = 500;      // C*m centers
static constexpr int RPT  = 8;        // rows per thread
static constexpr int QN   = 26;       // 25 col-quads + 1 rw col
static constexpr float SIGMA_INV = 0.1f;

__device__ __forceinline__ float aff1(float fk, float a, float b, float c,
                                      float d, float e) {
    const float d0 = fk - a, d1 = fk - b, d2 = fk - c, d3 = fk - d, d4 = fk - e;
    const float mv = fminf(fminf(fminf(d0 * d0, d1 * d1),
                                 fminf(d2 * d2, d3 * d3)), d4 * d4);
    return __expf(-mv * SIGMA_INV);
}

__global__ __launch_bounds__(256)
void affinity_kernel(const float* __restrict__ f,
                     const float* __restrict__ W,
                     float* __restrict__ out) {
    __shared__ float s_rw;
    const int tid = threadIdx.x;

    // ---- fused rw: wave 0 computes power sums over the 500 centers ----
    if (tid < 64) {
        double p1 = 0, p2 = 0, p3 = 0, p4 = 0;
        for (int i = tid; i < MC_; i += 64) {
            const double w  = (double)W[i];
            const double w2 = w * w;
            p1 += w; p2 += w2; p3 += w2 * w; p4 += w2 * w2;
        }
        for (int m = 32; m >= 1; m >>= 1) {
            p1 += __shfl_xor(p1, m);
            p2 += __shfl_xor(p2, m);
            p3 += __shfl_xor(p3, m);
            p4 += __shfl_xor(p4, m);
        }
        if (tid == 0) {
            const double mc = (double)MC_;
            const double P  = 0.5 * (mc * mc - mc);
            const double S1 = mc * p2 - p1 * p1;
            const double Sq = mc * p4 - 4.0 * p3 * p1 + 3.0 * p2 * p2;
            const double mu = S1 / P;
            s_rw = (float)(Sq / P - mu * mu);
        }
    }
    __syncthreads();
    const float rw = s_rw;

    // ---- streaming affinity ----
    const int t = blockIdx.x * 256 + tid;            // 0 .. 851967 (exact grid)
    const unsigned G = (unsigned)t / QN;             // row group (magic div)
    const int q = t - (int)G * QN;                   // 0..25
    const int qc = (q < 25) ? q : 0;                 // clamped quad for loads

    // W for clusters 4q..4q+3: 20 consecutive floats = 5 aligned float4 loads
    const float4* w4 = (const float4*)(W + qc * 20);
    const float4 wa = w4[0], wb = w4[1], wc = w4[2], wd = w4[3], we = w4[4];

    // 8 consecutive f values: two aligned float4 loads (L1 broadcast)
    const float4* f4 = (const float4*)f;
    const float4 fa = f4[G * 2 + 0];
    const float4 fb = f4[G * 2 + 1];
    const float fv[RPT] = {fa.x, fa.y, fa.z, fa.w, fb.x, fb.y, fb.z, fb.w};

    const size_t n0 = (size_t)G * RPT;
    if (q < 25) {
#pragma unroll
        for (int r = 0; r < RPT; ++r) {
            const float fk = fv[r];
            float4 o;
            o.x = aff1(fk, wa.x, wa.y, wa.z, wa.w, wb.x);  // cluster 4q+0
            o.y = aff1(fk, wb.y, wb.z, wb.w, wc.x, wc.y);  // cluster 4q+1
            o.z = aff1(fk, wc.z, wc.w, wd.x, wd.y, wd.z);  // cluster 4q+2
            o.w = aff1(fk, wd.w, we.x, we.y, we.z, we.w);  // cluster 4q+3
            *(float4*)(out + (n0 + r) * COLS + 4 * q) = o;
        }
    } else {
#pragma unroll
        for (int r = 0; r < RPT; ++r) {
            out[(n0 + r) * COLS + C_] = rw;
        }
    }
}

extern "C" void kernel_launch(void* const* d_in, const int* in_sizes, int n_in,
                              void* d_out, int out_size, void* d_ws, size_t ws_size,
                              hipStream_t stream) {
    const float* f   = (const float*)d_in[0];   // (262144, 1) fp32
    const float* W   = (const float*)d_in[1];   // (100, 5, 1) fp32
    float*       out = (float*)d_out;           // (262144, 101) fp32

    constexpr int T    = (N_ / RPT) * QN;       // 851,968 threads
    constexpr int grid = T / 256;               // 3328 blocks, exact
    affinity_kernel<<<grid, 256, 0, stream>>>(f, W, out);
}

// Round 5
// 121.856 us; speedup vs baseline: 1.0275x; 1.0275x over previous
//
#include <hip/hip_runtime.h>

// ClusteringAffinity: out[n,c] = exp(-min_j (f[n]-W[c,j])^2 / 10) for c<100,
// out[n,100] = rw (pairwise-variance regularizer over the 500 centers).
//
// R5 = R4 with the nontemporal-store type fixed: __builtin_nontemporal_store
// requires a native clang vector, not HIP's float4 class -> use
// ext_vector_type(4). Structure = R2 (best, 119.7 us): LDS tile ->
// contiguous aligned 16B stream (fill-kernel-identical store pattern).
//
// rw via power sums over the 500 scalar centers:
//   S1 = sum_{i<j}(wi-wj)^2 = mc*p2 - p1^2
//   Sq = sum_{i<j}(wi-wj)^4 = mc*p4 - 4*p3*p1 + 3*p2^2
//   mu = S1/P, rw = Sq/P - mu^2, P = (mc^2-mc)/2

static constexpr int N_    = 262144;
static constexpr int C_    = 100;
static constexpr int M_    = 5;
static constexpr int COLS  = C_ + 1;       // 101
static constexpr int MC_   = C_ * M_;      // 500
static constexpr int ROWS  = 64;           // rows per tile/block
static constexpr int TILE  = ROWS * COLS;  // 6464 floats = 25856 B (16B-aligned tiles)
static constexpr float SIGMA_INV = 0.1f;

typedef float floatx4 __attribute__((ext_vector_type(4)));  // native vector for nt store

__global__ __launch_bounds__(512)
void rw_kernel(const float* __restrict__ W, float* __restrict__ ws) {
    __shared__ double s1[512], s2[512], s3[512], s4[512];
    const int tid = threadIdx.x;
    double w = 0.0;
    if (tid < MC_) w = (double)W[tid];
    const double w2 = w * w;
    s1[tid] = w;
    s2[tid] = w2;
    s3[tid] = w2 * w;
    s4[tid] = w2 * w2;
    __syncthreads();
    for (int off = 256; off > 0; off >>= 1) {
        if (tid < off) {
            s1[tid] += s1[tid + off];
            s2[tid] += s2[tid + off];
            s3[tid] += s3[tid + off];
            s4[tid] += s4[tid + off];
        }
        __syncthreads();
    }
    if (tid == 0) {
        const double p1 = s1[0], p2 = s2[0], p3 = s3[0], p4 = s4[0];
        const double mc = (double)MC_;
        const double P  = 0.5 * (mc * mc - mc);
        const double S1 = mc * p2 - p1 * p1;
        const double Sq = mc * p4 - 4.0 * p3 * p1 + 3.0 * p2 * p2;
        const double mu = S1 / P;
        ws[0] = (float)(Sq / P - mu * mu);
    }
}

__global__ __launch_bounds__(256)
void affinity_kernel(const float* __restrict__ f,
                     const float* __restrict__ W,
                     const float* __restrict__ ws,
                     float* __restrict__ out) {
    __shared__ __align__(16) float tile[TILE];
    const int t  = threadIdx.x;
    const int n0 = blockIdx.x * ROWS;

    // ---- compute phase: threads 0..201 each own one column for 32 rows ----
    if (t < 2 * COLS) {
        const int rh = (t >= COLS) ? 1 : 0;       // row half: rows rh*32..rh*32+31
        const int c  = t - rh * COLS;             // 0..100
        float* trow = tile + rh * 32 * COLS + c;

        if (c < C_) {
            // 32 consecutive f values: 8 aligned float4 loads (L1-broadcast)
            float fv[32];
            const float4* f4 = (const float4*)(f + n0 + rh * 32);
#pragma unroll
            for (int q = 0; q < 8; ++q) {
                const float4 v = f4[q];
                fv[q * 4 + 0] = v.x; fv[q * 4 + 1] = v.y;
                fv[q * 4 + 2] = v.z; fv[q * 4 + 3] = v.w;
            }
            const float w0 = W[c * M_ + 0];
            const float w1 = W[c * M_ + 1];
            const float w2 = W[c * M_ + 2];
            const float w3 = W[c * M_ + 3];
            const float w4 = W[c * M_ + 4];
#pragma unroll
            for (int i = 0; i < 32; ++i) {
                const float fk = fv[i];
                const float d0 = fk - w0, d1 = fk - w1, d2 = fk - w2,
                            d3 = fk - w3, d4 = fk - w4;
                const float m01 = fminf(d0 * d0, d1 * d1);
                const float m23 = fminf(d2 * d2, d3 * d3);
                const float mv  = fminf(fminf(m01, m23), d4 * d4);
                trow[i * COLS] = __expf(-mv * SIGMA_INV);  // consecutive-c -> conflict-free
            }
        } else {
            const float rw = ws[0];                // rw column: writes only
#pragma unroll
            for (int i = 0; i < 32; ++i) trow[i * COLS] = rw;
        }
    }
    __syncthreads();

    // ---- write phase: stream tile to global as aligned contiguous 16B nt stores ----
    // Identical address pattern to the 6.4 TB/s fill kernel; nt = write-once.
    const floatx4* lsrc = (const floatx4*)tile;
    floatx4* gdst = (floatx4*)(out + (size_t)n0 * COLS);  // blk*25856 B, 16B-aligned
    constexpr int NV = TILE / 4;  // 1616 vectors
#pragma unroll
    for (int q = 0; q < 6; ++q) {
        const int j = q * 256 + t;
        __builtin_nontemporal_store(lsrc[j], gdst + j);
    }
    {
        const int j = 6 * 256 + t;
        if (j < NV) __builtin_nontemporal_store(lsrc[j], gdst + j);
    }
}

extern "C" void kernel_launch(void* const* d_in, const int* in_sizes, int n_in,
                              void* d_out, int out_size, void* d_ws, size_t ws_size,
                              hipStream_t stream) {
    const float* f   = (const float*)d_in[0];   // (262144, 1) fp32
    const float* W   = (const float*)d_in[1];   // (100, 5, 1) fp32
    float*       out = (float*)d_out;           // (262144, 101) fp32
    float*       ws  = (float*)d_ws;

    rw_kernel<<<1, 512, 0, stream>>>(W, ws);
    affinity_kernel<<<N_ / ROWS, 256, 0, stream>>>(f, W, ws, out);
}